// Round 8
// baseline (414.223 us; speedup 1.0000x reference)
//
#include <hip/hip_runtime.h>

// LinearAttention bf16-MFMA pipeline. 256x256 GEMM, BK=64, 8-phase schedule.
// R17 = R16 core (best wall 407.5us, gemm8 byte-identical) + aux trim:
//   - cvt_x grid-stride @2048 blocks (was 32768 one-shot tiny blocks)
//   - add_ctx grid-stride @1024 blocks (was 4096)
//   - den memset moved to stream head
// R16 post-mortem: KV-merge banked -6.8us via dispatch-boundary elimination
// (FETCH actually rose; the win was boundary, not L2 pairing).
// Structural constraints (derived this round, ending schedule surgery):
//   * depth-3 prefetch (m201's vmcnt(6)) is NOT safely reconstructible at
//     256^2/BK=64 dbuf: row-half schedule races (t+1).Ah vs ph5 wm=1 reads;
//     kk-half staging needs non-linear gld_lds dests (impossible) or a
//     [rows][64B] layout that is provably >=8-way bank-conflicted; a 3rd
//     buffer needs 192KB > 160KB. vmcnt(2)@ph3/ph7 is the minimal drain for
//     the 2-ahead ledger (ph2's Ah must land before ph4's buf1.A reads).
//   * acc(128 AGPR)+VGPR(128) = 256/wave exactly -> 2 waves/SIMD hard cap;
//     any reg-staging fusion (cvt_x fold, add_ctx fold) spills (R13 mode).
//
// B=8, S=4096, D=1024, F=1024.
// out[b,f,s] = sum_g ctxRaw[b,f,g] * Qs[b,s,g]
//   ctxRaw = K^T V (unscaled);  Qs = (relu(x@Wq)+1)/(den+eps)
//   den[b,g] = sum_s K[b,s,g];  K = relu(x@Wk)+1;  V = x@Wv
// All GEMMs: C[M][N] = sum_k A[M][K] * Bt[N][K]  (NT, both row-major bf16).
//
// K-loop ledger: identical to R10/R14/R16 — reg-pipelined 8 phases,
// 1 barrier/phase, vmcnt(2) publishes at ph3/ph7.

#define EPSF 1e-6f

constexpr int Bb = 8;
constexpr int Ss = 4096;
constexpr int Dd = 1024;
constexpr int Ff = 1024;

typedef __attribute__((ext_vector_type(8))) short   bf16x8;
typedef __attribute__((ext_vector_type(8))) unsigned short u16x8;
typedef __attribute__((ext_vector_type(4))) float   f32x4;

// explicit LDS (addrspace 3) pointer types
typedef __attribute__((address_space(3))) unsigned char lds_u8;
typedef __attribute__((address_space(3))) const bf16x8  lds_cvec;

static __device__ __forceinline__ unsigned short f2bf(float f) {
    union { float f; unsigned int u; } v; v.f = f;
    unsigned int r = (v.u + 0x7fffu + ((v.u >> 16) & 1u)) >> 16;
    return (unsigned short)r;
}
static __device__ __forceinline__ float bf2f(unsigned short u) {
    union { unsigned int u; float f; } v; v.u = ((unsigned int)u) << 16;
    return v.f;
}

static __device__ __forceinline__ void gld_lds16(const void* g, lds_u8* l) {
    __builtin_amdgcn_global_load_lds(
        (const __attribute__((address_space(1))) unsigned int*)g,
        (__attribute__((address_space(3))) unsigned int*)l,
        16, 0, 0);
}

// ---------------------------------------------------------------------------
// grid-stride: 2048 blocks x 256 thr; each iter converts one float4 -> ushort4
__global__ __launch_bounds__(256)
void cvt_x_kernel(const float* __restrict__ x, unsigned short* __restrict__ xb, int n4)
{
    const int stride = gridDim.x * blockDim.x;
    for (int i = blockIdx.x * blockDim.x + threadIdx.x; i < n4; i += stride) {
        float4 v = *(const float4*)&x[(size_t)i * 4];
        ushort4 o;
        o.x = f2bf(v.x); o.y = f2bf(v.y); o.z = f2bf(v.z); o.w = f2bf(v.w);
        *(ushort4*)&xb[(size_t)i * 4] = o;
    }
}

// W[d][f] fp32 -> WT[f][d] bf16 (x3 weights)
__global__ void cvt_wT_kernel(const float* __restrict__ Wq,
                              const float* __restrict__ Wk,
                              const float* __restrict__ Wv,
                              unsigned short* __restrict__ WT)
{
    const int z = blockIdx.z;
    const float* __restrict__ W = (z == 0) ? Wq : (z == 1 ? Wk : Wv);
    unsigned short* __restrict__ dst = WT + (size_t)z * Dd * Ff;

    __shared__ float tile[32][33];
    const int tid = threadIdx.x;
    const int d0 = blockIdx.y * 32, f0 = blockIdx.x * 32;
    const int c = tid & 31, r8 = tid >> 5;
#pragma unroll
    for (int p = 0; p < 4; ++p) {
        int r = p * 8 + r8;
        tile[r][c] = W[(size_t)(d0 + r) * Ff + f0 + c];
    }
    __syncthreads();
#pragma unroll
    for (int p = 0; p < 4; ++p) {
        int r = p * 8 + r8;
        dst[(size_t)(f0 + r) * Dd + d0 + c] = f2bf(tile[c][r]);
    }
}

// ctx[b] = p[2b] + p[2b+1]  (bf16 split-K partials), grid-stride over all b
__global__ __launch_bounds__(256)
void add_ctx_kernel(const unsigned short* __restrict__ p,
                    unsigned short* __restrict__ c, int n8)
{
    const int stride = gridDim.x * blockDim.x;
    for (int i = blockIdx.x * blockDim.x + threadIdx.x; i < n8; i += stride) {
        const int b = i / (Ff * Ff / 8);
        const size_t i8 = (size_t)i * 8 - (size_t)b * Ff * Ff;  // offset within batch
        const u16x8 a0 = *(const u16x8*)(p + (size_t)(2 * b) * Ff * Ff + i8);
        const u16x8 a1 = *(const u16x8*)(p + (size_t)(2 * b + 1) * Ff * Ff + i8);
        u16x8 o;
#pragma unroll
        for (int j = 0; j < 8; ++j) o[j] = f2bf(bf2f(a0[j]) + bf2f(a1[j]));
        *(u16x8*)(c + (size_t)b * Ff * Ff + i8) = o;
    }
}

// ---------------------------------------------------------------------------
// 256x256 NT bf16 MFMA GEMM, 512 threads, 8 waves (2M x 4N), BK=64, 8-phase,
// register-pipelined (frags read one phase ahead), 1 barrier/phase.
// LDS: buf0.A@0 buf0.B@32K buf1.A@64K buf1.B@96K; each [256 rows][128B],
// 16B-chunk XOR-swizzle key=(row&7). MFMA swapped operands (C^T frags).
// KVSEL=1: z encodes (b = z>>1, pid = z&1); pid selects Wk/Wv A-slice and
// KbT/VbT output slab; relu+1 and den-atomics only for pid==0 (runtime,
// block-uniform). DENACC/ACT templates still used by non-merged variants.
template<int ACT, int SCALE, int OUT_BF16, int SPLITK2, int DENACC, int KVSEL>
__global__ __launch_bounds__(512, 2)
void gemm8(const unsigned short* __restrict__ A,
           const unsigned short* __restrict__ Bt,
           void* __restrict__ Cout,
           const float* __restrict__ den,
           float* __restrict__ denw,
           int lda, int ldb, int ldc, int Kdim,
           size_t strideA, size_t strideB, size_t strideC)
{
    __shared__ __align__(16) unsigned char smem_[131072];
    lds_u8* const smem = (lds_u8*)smem_;

    // ---- XCD-aware bijective block swizzle (total blocks % 8 == 0 always)
    const int gx = gridDim.x, gxy = gx * gridDim.y;
    int flat = blockIdx.z * gxy + blockIdx.y * gx + blockIdx.x;
    const int nwg = gxy * gridDim.z;
    const int cpx = nwg >> 3;
    flat = (flat & 7) * cpx + (flat >> 3);
    const int z = flat / gxy;
    const int rem = flat - z * gxy;
    const int by = rem / gx;
    const int bx = rem - by * gx;

    const int pid  = KVSEL ? (z & 1) : 0;
    const int zb   = KVSEL ? (z >> 1) : (SPLITK2 ? (z >> 1) : z);
    const int koff = SPLITK2 ? ((z & 1) * Kdim) : 0;
    const size_t cslab = KVSEL ? (size_t)(pid * Bb + zb) : (size_t)z;

    const unsigned short* __restrict__ Ag  =
        A + strideA * zb + koff + (KVSEL ? (size_t)pid * Dd * Ff : 0);
    const unsigned short* __restrict__ Bg  = Bt + strideB * zb + koff;
    const float* __restrict__ denb = SCALE ? (den + (size_t)zb * Ff) : nullptr;

    const int bm = by * 256;
    const int bn = bx * 256;

    const int tid  = threadIdx.x;
    const int wv   = tid >> 6, lane = tid & 63;
    const int wm   = wv >> 2, wn = wv & 3;        // 2 x 4 wave grid
    const int lm   = lane & 15;
    const int kg16 = (lane >> 4) << 4;            // k-group byte offset
    const int swz  = (lm & 7) << 4;               // read-side XOR key (row&7)
    const int kbs  = (((tid & 7) ^ ((tid >> 3) & 7)) << 4);  // stage src chunk
    const int srow = tid >> 3;                    // stage row within 64-row q-block

    f32x4 acc[8][4];
#pragma unroll
    for (int i = 0; i < 8; ++i)
#pragma unroll
        for (int j = 0; j < 4; ++j) acc[i][j] = (f32x4){0.f, 0.f, 0.f, 0.f};

    lds_u8* const A0 = smem;
    lds_u8* const B0 = smem + 32768;
    lds_u8* const A1 = smem + 65536;
    lds_u8* const B1 = smem + 98304;

    // stage one half-tile (16KB, 2 gld_lds16/thread) of K-tile ts.
    // m: 0=A 1=B; buf: 0/1; h: 0=rows0-127 1=rows128-255.
    auto STAGE = [&](int ts, int m, int buf, int h) {
        const unsigned short* gb = m ? Bg : Ag;
        const int ld = m ? ldb : lda;
        const int off0 = m ? bn : bm;
        lds_u8* lb = smem + buf * 65536 + m * 32768 + h * 16384 + wv * 1024;
#pragma unroll
        for (int q = 0; q < 2; ++q) {
            int row = h * 128 + q * 64 + srow;
            const unsigned char* g =
                (const unsigned char*)(gb + (size_t)(off0 + row) * ld + ts * 64) + kbs;
            gld_lds16(g, lb + q * 8192);
        }
    };
    auto LDA4 = [&](bf16x8* dst, int fmb, int kk, lds_u8* Ab) {
#pragma unroll
        for (int f = 0; f < 4; ++f) {
            int r = wm * 128 + (fmb + f) * 16 + lm;
            dst[f] = *(lds_cvec*)(Ab + r * 128 + ((kk * 64 + kg16) ^ swz));
        }
    };
    auto LDB4 = [&](bf16x8* dst, int kk, lds_u8* Bb) {
#pragma unroll
        for (int f = 0; f < 4; ++f) {
            int c = wn * 64 + f * 16 + lm;
            dst[f] = *(lds_cvec*)(Bb + c * 128 + ((kk * 64 + kg16) ^ swz));
        }
    };

    // swapped operands: D frag = C^T block (rows=N, cols=M)
#define MM16(a4, b4, mo)                                                        \
    do {                                                                        \
        __builtin_amdgcn_s_setprio(1);                                          \
        _Pragma("unroll")                                                       \
        for (int fm = 0; fm < 4; ++fm)                                          \
            _Pragma("unroll")                                                   \
            for (int fn = 0; fn < 4; ++fn)                                      \
                acc[(mo) + fm][fn] = __builtin_amdgcn_mfma_f32_16x16x32_bf16(   \
                    (b4)[fn], (a4)[fm], acc[(mo) + fm][fn], 0, 0, 0);           \
        __builtin_amdgcn_s_setprio(0);                                          \
    } while (0)

    // phase tail: drain own ds_reads, pin so nothing crosses, then the single
    // per-phase barrier. PHEND_VM2 also drains vmem to 2 outstanding
    // (buffer publish, per R10 ledger).
#define PHEND()                                                     \
    do {                                                            \
        asm volatile("s_waitcnt lgkmcnt(0)");                       \
        __builtin_amdgcn_sched_barrier(0);                          \
        __builtin_amdgcn_s_barrier();                               \
    } while (0)
#define PHEND_VM2()                                                 \
    do {                                                            \
        asm volatile("s_waitcnt vmcnt(2) lgkmcnt(0)");              \
        __builtin_amdgcn_sched_barrier(0);                          \
        __builtin_amdgcn_s_barrier();                               \
    } while (0)

    const int NT = Kdim >> 6;   // K-tiles of 64 (even, >= 8 here)
    const int NI = NT >> 1;

    // prologue: t0 {Bl,Bh,Al,Ah} -> buf0, t1 {Bl,Bh} -> buf1  (12 loads)
    STAGE(0, 1, 0, 0); STAGE(0, 1, 0, 1);
    STAGE(0, 0, 0, 0); STAGE(0, 0, 0, 1);
    STAGE(1, 1, 1, 0); STAGE(1, 1, 1, 1);
    asm volatile("s_waitcnt vmcnt(4)");      // t0 fully landed
    __builtin_amdgcn_s_barrier();

    bf16x8 a03[4], a47[4], b0[4], b1[4];
    // pre-read ph1 frags (tile 0, kk0, buf0)
    LDB4(b0, 0, B0); LDA4(a03, 0, 0, A0);

    for (int i = 0; i < NI; ++i) {
        const int t = 2 * i;
        const int t1s = t + 1;                       // always < NT
        const int t2s = (t + 2 < NT) ? t + 2 : NT - 1;
        const int t3s = (t + 3 < NT) ? t + 3 : NT - 1;

        // ph1
        STAGE(t1s, 0, 1, 0);
        LDA4(a47, 4, 0, A0);
        MM16(a03, b0, 0);
        PHEND();
        // ph2
        STAGE(t1s, 0, 1, 1);
        LDA4(a03, 0, 1, A0); LDB4(b1, 1, B0);
        MM16(a47, b0, 4);
        PHEND();
        // ph3  (publishes buf1 = tile t+1)
        STAGE(t2s, 1, 0, 0);
        LDA4(a47, 4, 1, A0);
        MM16(a03, b1, 0);
        PHEND_VM2();
        // ph4
        STAGE(t2s, 1, 0, 1);
        LDA4(a03, 0, 0, A1); LDB4(b0, 0, B1);
        MM16(a47, b1, 4);
        PHEND();
        // ph5
        STAGE(t2s, 0, 0, 0);
        LDA4(a47, 4, 0, A1);
        MM16(a03, b0, 0);
        PHEND();
        // ph6
        STAGE(t2s, 0, 0, 1);
        LDA4(a03, 0, 1, A1); LDB4(b1, 1, B1);
        MM16(a47, b0, 4);
        PHEND();
        // ph7  (publishes buf0 = tile t+2)
        STAGE(t3s, 1, 1, 0);
        LDA4(a47, 4, 1, A1);
        MM16(a03, b1, 0);
        PHEND_VM2();
        // ph8
        STAGE(t3s, 1, 1, 1);
        LDA4(a03, 0, 0, A0); LDB4(b0, 0, B0);   // next tile's ph1 frags
        MM16(a47, b1, 4);
        PHEND();
    }

    asm volatile("s_waitcnt vmcnt(0)");

    // ---- epilogue (swapped layout): frag (fm,fn):
    // row m = bm + wm*128 + fm*16 + lm ; cols n = bn + wn*64 + fn*16 + (lane>>4)*4
    const bool actv = ACT || (KVSEL && pid == 0);
    const bool dacc = DENACC || (KVSEL && pid == 0);
    const int hi4 = (lane >> 4) * 4;
#pragma unroll
    for (int fm = 0; fm < 8; ++fm) {
        const int gr = bm + wm * 128 + fm * 16 + lm;
        float rowsum = 0.f;
#pragma unroll
        for (int fn = 0; fn < 4; ++fn) {
            const int gcn = bn + wn * 64 + fn * 16 + hi4;
            f32x4 v = acc[fm][fn];
            if (actv) {
#pragma unroll
                for (int e = 0; e < 4; ++e) v[e] = fmaxf(v[e], 0.f) + 1.f;
            }
            if (dacc) rowsum += v[0] + v[1] + v[2] + v[3];
            if (SCALE) {
                float4 d4 = *(const float4*)&denb[gcn];
                v[0] *= 1.f / (d4.x + EPSF);
                v[1] *= 1.f / (d4.y + EPSF);
                v[2] *= 1.f / (d4.z + EPSF);
                v[3] *= 1.f / (d4.w + EPSF);
            }
            if (OUT_BF16) {
                ushort4 o;
                o.x = f2bf(v[0]); o.y = f2bf(v[1]); o.z = f2bf(v[2]); o.w = f2bf(v[3]);
                *(ushort4*)((unsigned short*)Cout + strideC * cslab + (size_t)gr * ldc + gcn) = o;
            } else {
                *(float4*)((float*)Cout + strideC * cslab + (size_t)gr * ldc + gcn) =
                    *(float4*)&v;
            }
        }
        if (dacc) {
            // lanes {lm, lm+16, lm+32, lm+48} share gr; reduce across them
            rowsum += __shfl_xor(rowsum, 16, 64);
            rowsum += __shfl_xor(rowsum, 32, 64);
            if (lane < 16) atomicAdd(denw + (size_t)zb * Ff + gr, rowsum);
        }
    }
#undef MM16
#undef PHEND
#undef PHEND_VM2
}

// ---------------------------------------------------------------------------
extern "C" void kernel_launch(void* const* d_in, const int* in_sizes, int n_in,
                              void* d_out, int out_size, void* d_ws, size_t ws_size,
                              hipStream_t stream)
{
    (void)in_sizes; (void)n_in; (void)out_size;
    const float* x  = (const float*)d_in[0];
    const float* Wq = (const float*)d_in[1];
    const float* Wk = (const float*)d_in[2];
    const float* Wv = (const float*)d_in[3];
    float* out = (float*)d_out;

    const size_t nx   = (size_t)Bb * Ss * Dd;
    const size_t nW   = (size_t)3 * Dd * Ff;
    const size_t nQKV = (size_t)Bb * Ss * Ff;
    const size_t nCtx = (size_t)Bb * Ff * Ff;
    const size_t nP   = (size_t)16 * Ff * Ff;   // split-K partials (bf16)

    unsigned short* xb   = (unsigned short*)d_ws;          // [B][S][D]
    unsigned short* WT   = xb + nx;                        // [3][F][D]
    unsigned short* Qb   = WT + nW;                        // [B][S][F] (den-scaled)
    unsigned short* KbT  = Qb + nQKV;                      // [B][F][S]
    unsigned short* VbT  = KbT + nQKV;                     // [B][F][S]  (adjacent to KbT!)
    unsigned short* ctxb = VbT + nQKV;                     // [B][F][F]
    float* den = (float*)(ctxb + nCtx);                    // [B][F]
    unsigned short* pctx = (unsigned short*)(den + (size_t)Bb * Ff); // [16][F][F]

    const size_t need_split =
        ((nx + nW + 3 * nQKV + nCtx + nP) * 2 + (size_t)Bb * Ff * 4);
    const bool do_split = ws_size >= need_split;

    // den accumulated by K-projection epilogue atomics — zero it first.
    hipMemsetAsync(den, 0, (size_t)Bb * Ff * sizeof(float), stream);

    cvt_x_kernel<<<dim3(2048), 256, 0, stream>>>(x, xb, (int)(nx / 4));
    cvt_wT_kernel<<<dim3(Ff / 32, Dd / 32, 3), 256, 0, stream>>>(Wq, Wk, Wv, WT);

    // Merged K+V projections (KVSEL=1): z = b*2 + pid; pid0 -> KbT (relu+1,
    // den atomics), pid1 -> VbT (plain). A base = Wk slice; pid adds D*F.
    // C base = KbT; slab = pid*Bb + b (VbT adjacent to KbT in ws).
    gemm8<0, 0, 1, 0, 0, 1><<<dim3(Ss / 256, Ff / 256, 2 * Bb), 512, 0, stream>>>(
        WT + (size_t)1 * Dd * Ff, xb, KbT, nullptr, den,
        Dd, Dd, Ss, Dd, 0, (size_t)Ss * Dd, (size_t)Ff * Ss);

    // Qs[s][f] = relu1(x @ Wq) / (den[f]+eps)
    gemm8<1, 1, 1, 0, 0, 0><<<dim3(Ff / 256, Ss / 256, Bb), 512, 0, stream>>>(
        xb, WT + (size_t)0 * Dd * Ff, Qb, den, nullptr,
        Dd, Dd, Ff, Dd, (size_t)Ss * Dd, 0, (size_t)Ss * Ff);

    // ctxRaw[f][g] = K^T V  (split-K=2 -> 256 blocks)
    if (do_split) {
        gemm8<0, 0, 1, 1, 0, 0><<<dim3(Ff / 256, Ff / 256, 2 * Bb), 512, 0, stream>>>(
            KbT, VbT, pctx, nullptr, nullptr,
            Ss, Ss, Ff, Ss / 2, (size_t)Ff * Ss, (size_t)Ff * Ss, (size_t)Ff * Ff);
        add_ctx_kernel<<<dim3(1024), 256, 0, stream>>>(
            pctx, ctxb, (int)((size_t)Bb * Ff * Ff / 8));
    } else {
        gemm8<0, 0, 1, 0, 0, 0><<<dim3(Ff / 256, Ff / 256, Bb), 512, 0, stream>>>(
            KbT, VbT, ctxb, nullptr, nullptr,
            Ss, Ss, Ff, Ss, (size_t)Ff * Ss, (size_t)Ff * Ss, (size_t)Ff * Ff);
    }

    // out[f][s] = ctxRaw @ Qs^T (fp32 out)
    gemm8<0, 0, 0, 0, 0, 0><<<dim3(Ss / 256, Ff / 256, Bb), 512, 0, stream>>>(
        ctxb, Qb, out, nullptr, nullptr,
        Ff, Ff, Ss, Ff, (size_t)Ff * Ff, (size_t)Ss * Ff, (size_t)Ff * Ss);
}

// Round 9
// 406.596 us; speedup vs baseline: 1.0188x; 1.0188x over previous
//
#include <hip/hip_runtime.h>

// LinearAttention bf16-MFMA pipeline. 256x256 GEMM, BK=64, 8-phase schedule.
// R18 = R16 core+aux (best wall 407.5us) + QKV-merged projections + den-scale
// moved from Q to ctx (reference-faithful: context = num/(den+eps)).
//   * Scaling ctx (not Q) removes Q-proj's den dependency -> Q merges into
//     the projection dispatch (QKV=1, grid z=3B: pid=z%3 0=Q,1=K,2=V).
//     Same-(bx,by) blocks of all pids share the 512KB xb panel on the SAME
//     XCD (dflat=64 = 0 mod 8). One fewer dispatch boundary (the only lever
//     that moved wall: R16 -6.8us).
//   * den-scale applied in add_ctx (split-K path) / ctx-GEMM SCALE epilogue
//     (fallback). Stream order guarantees den complete. Numerics improve:
//     ctx stored bf16 at O(1) (step ~0.004) vs raw O(4096) (step ~16).
//   * R17 aux rewrites reverted (they regressed ~7us): cvt_x one-shot grid,
//     add_ctx per-batch grid.
// Structural constraints (R17, unchanged): depth-3 prefetch not safely
// reconstructible at 256^2/BK=64 dbuf; acc(128 AGPR)+128 VGPR = 256/wave
// -> 2 waves/SIMD hard cap; vmcnt(2)@ph3/ph7 minimal for 2-ahead ledger.
//
// B=8, S=4096, D=1024, F=1024.
// out[b,f,s] = sum_g ctx[b,f,g] * Q[b,s,g]
//   ctx = (K^T V)/(den+eps);  Q = relu(x@Wq)+1
//   den[b,g] = sum_s K[b,s,g];  K = relu(x@Wk)+1;  V = x@Wv
// All GEMMs: C[M][N] = sum_k A[M][K] * Bt[N][K]  (NT, both row-major bf16).
//
// K-loop ledger: identical to R10/R14/R16 — reg-pipelined 8 phases,
// 1 barrier/phase, vmcnt(2) publishes at ph3/ph7.

#define EPSF 1e-6f

constexpr int Bb = 8;
constexpr int Ss = 4096;
constexpr int Dd = 1024;
constexpr int Ff = 1024;

typedef __attribute__((ext_vector_type(8))) short   bf16x8;
typedef __attribute__((ext_vector_type(8))) unsigned short u16x8;
typedef __attribute__((ext_vector_type(4))) float   f32x4;

// explicit LDS (addrspace 3) pointer types
typedef __attribute__((address_space(3))) unsigned char lds_u8;
typedef __attribute__((address_space(3))) const bf16x8  lds_cvec;

static __device__ __forceinline__ unsigned short f2bf(float f) {
    union { float f; unsigned int u; } v; v.f = f;
    unsigned int r = (v.u + 0x7fffu + ((v.u >> 16) & 1u)) >> 16;
    return (unsigned short)r;
}
static __device__ __forceinline__ float bf2f(unsigned short u) {
    union { unsigned int u; float f; } v; v.u = ((unsigned int)u) << 16;
    return v.f;
}

static __device__ __forceinline__ void gld_lds16(const void* g, lds_u8* l) {
    __builtin_amdgcn_global_load_lds(
        (const __attribute__((address_space(1))) unsigned int*)g,
        (__attribute__((address_space(3))) unsigned int*)l,
        16, 0, 0);
}

// ---------------------------------------------------------------------------
__global__ void cvt_x_kernel(const float* __restrict__ x, unsigned short* __restrict__ xb, int n4)
{
    int i = blockIdx.x * blockDim.x + threadIdx.x;
    if (i >= n4) return;
    float4 v = *(const float4*)&x[(size_t)i * 4];
    ushort4 o;
    o.x = f2bf(v.x); o.y = f2bf(v.y); o.z = f2bf(v.z); o.w = f2bf(v.w);
    *(ushort4*)&xb[(size_t)i * 4] = o;
}

// W[d][f] fp32 -> WT[f][d] bf16 (x3 weights)
__global__ void cvt_wT_kernel(const float* __restrict__ Wq,
                              const float* __restrict__ Wk,
                              const float* __restrict__ Wv,
                              unsigned short* __restrict__ WT)
{
    const int z = blockIdx.z;
    const float* __restrict__ W = (z == 0) ? Wq : (z == 1 ? Wk : Wv);
    unsigned short* __restrict__ dst = WT + (size_t)z * Dd * Ff;

    __shared__ float tile[32][33];
    const int tid = threadIdx.x;
    const int d0 = blockIdx.y * 32, f0 = blockIdx.x * 32;
    const int c = tid & 31, r8 = tid >> 5;
#pragma unroll
    for (int p = 0; p < 4; ++p) {
        int r = p * 8 + r8;
        tile[r][c] = W[(size_t)(d0 + r) * Ff + f0 + c];
    }
    __syncthreads();
#pragma unroll
    for (int p = 0; p < 4; ++p) {
        int r = p * 8 + r8;
        dst[(size_t)(f0 + r) * Dd + d0 + c] = f2bf(tile[c][r]);
    }
}

// ctx[b][f][g] = (p[2b] + p[2b+1]) / (den[b][g] + eps)   (bf16 partials)
__global__ void add_ctx_kernel(const unsigned short* __restrict__ p,
                               unsigned short* __restrict__ c,
                               const float* __restrict__ den)
{
    const int b = blockIdx.y;
    const size_t i8 = ((size_t)blockIdx.x * 256 + threadIdx.x) * 8;
    const int g0 = (int)(i8 & (size_t)(Ff - 1));
    const u16x8 a0 = *(const u16x8*)(p + (size_t)(2 * b) * Ff * Ff + i8);
    const u16x8 a1 = *(const u16x8*)(p + (size_t)(2 * b + 1) * Ff * Ff + i8);
    const float4 d0 = *(const float4*)&den[(size_t)b * Ff + g0];
    const float4 d1 = *(const float4*)&den[(size_t)b * Ff + g0 + 4];
    const float dv[8] = {d0.x, d0.y, d0.z, d0.w, d1.x, d1.y, d1.z, d1.w};
    u16x8 o;
#pragma unroll
    for (int j = 0; j < 8; ++j)
        o[j] = f2bf((bf2f(a0[j]) + bf2f(a1[j])) * (1.f / (dv[j] + EPSF)));
    *(u16x8*)(c + (size_t)b * Ff * Ff + i8) = o;
}

// ---------------------------------------------------------------------------
// 256x256 NT bf16 MFMA GEMM, 512 threads, 8 waves (2M x 4N), BK=64, 8-phase,
// register-pipelined (frags read one phase ahead), 1 barrier/phase.
// LDS: buf0.A@0 buf0.B@32K buf1.A@64K buf1.B@96K; each [256 rows][128B],
// 16B-chunk XOR-swizzle key=(row&7). MFMA swapped operands (C^T frags).
// QKV=1: z = 3*b + pid; pid 0=Q (A-op=xb, B-op=Wq, C=Qb[S][F], bx<->by roles),
// 1=K (relu1+den atomics, C=KbT[F][S]), 2=V (plain, C=VbT[F][S]).
// A param = WT base (Wq at +0, Wk at +D*F, Wv at +2*D*F); Bt param = xb;
// Cout param = Qb (KbT/VbT adjacent at +p*B*S*F). All block-uniform branches.
template<int ACT, int SCALE, int OUT_BF16, int SPLITK2, int DENACC, int QKV>
__global__ __launch_bounds__(512, 2)
void gemm8(const unsigned short* __restrict__ A,
           const unsigned short* __restrict__ Bt,
           void* __restrict__ Cout,
           const float* __restrict__ den,
           float* __restrict__ denw,
           int lda, int ldb, int ldc, int Kdim,
           size_t strideA, size_t strideB, size_t strideC)
{
    __shared__ __align__(16) unsigned char smem_[131072];
    lds_u8* const smem = (lds_u8*)smem_;

    // ---- XCD-aware bijective block swizzle (total blocks % 8 == 0 always)
    const int gx = gridDim.x, gxy = gx * gridDim.y;
    int flat = blockIdx.z * gxy + blockIdx.y * gx + blockIdx.x;
    const int nwg = gxy * gridDim.z;
    const int cpx = nwg >> 3;
    flat = (flat & 7) * cpx + (flat >> 3);
    const int z = flat / gxy;
    const int rem = flat - z * gxy;
    const int by = rem / gx;
    const int bx = rem - by * gx;

    const int pid  = QKV ? (z % 3) : 0;
    const int zb   = QKV ? (z / 3) : (SPLITK2 ? (z >> 1) : z);
    const int koff = SPLITK2 ? ((z & 1) * Kdim) : 0;

    const unsigned short* __restrict__ Ag;
    const unsigned short* __restrict__ Bg;
    int bm, bn, ldcr;
    size_t coff;
    bool actv, dacc;
    if (QKV) {
        if (pid == 0) {          // Q: C[S][F] = relu1(xb @ WqT^T)
            Ag = Bt + (size_t)zb * Ss * Dd;      // xb slab
            Bg = A;                              // Wq slice (offset 0)
            bm = bx * 256; bn = by * 256;        // swapped roles: x spans M=S
            ldcr = Ff;
            coff = (size_t)zb * Ss * Ff;
            actv = true;  dacc = false;
        } else {                 // K/V: C[F][S] = (Wk/v^T @ xb^T)
            Ag = A + (size_t)pid * Dd * Ff;      // Wk (pid1) / Wv (pid2)
            Bg = Bt + (size_t)zb * Ss * Dd;
            bm = by * 256; bn = bx * 256;
            ldcr = Ss;
            coff = ((size_t)pid * Bb + zb) * ((size_t)Ff * Ss);  // KbT/VbT slabs
            actv = (pid == 1); dacc = (pid == 1);
        }
    } else {
        Ag = A + strideA * zb + koff;
        Bg = Bt + strideB * zb + koff;
        bm = by * 256; bn = bx * 256;
        ldcr = ldc;
        coff = strideC * (size_t)z;
        actv = ACT; dacc = DENACC;
    }
    const float* __restrict__ denb = SCALE ? (den + (size_t)zb * Ff) : nullptr;

    const int tid  = threadIdx.x;
    const int wv   = tid >> 6, lane = tid & 63;
    const int wm   = wv >> 2, wn = wv & 3;        // 2 x 4 wave grid
    const int lm   = lane & 15;
    const int kg16 = (lane >> 4) << 4;            // k-group byte offset
    const int swz  = (lm & 7) << 4;               // read-side XOR key (row&7)
    const int kbs  = (((tid & 7) ^ ((tid >> 3) & 7)) << 4);  // stage src chunk
    const int srow = tid >> 3;                    // stage row within 64-row q-block

    f32x4 acc[8][4];
#pragma unroll
    for (int i = 0; i < 8; ++i)
#pragma unroll
        for (int j = 0; j < 4; ++j) acc[i][j] = (f32x4){0.f, 0.f, 0.f, 0.f};

    lds_u8* const A0 = smem;
    lds_u8* const B0 = smem + 32768;
    lds_u8* const A1 = smem + 65536;
    lds_u8* const B1 = smem + 98304;

    // stage one half-tile (16KB, 2 gld_lds16/thread) of K-tile ts.
    // m: 0=A 1=B; buf: 0/1; h: 0=rows0-127 1=rows128-255.
    auto STAGE = [&](int ts, int m, int buf, int h) {
        const unsigned short* gb = m ? Bg : Ag;
        const int ld = m ? ldb : lda;
        const int off0 = m ? bn : bm;
        lds_u8* lb = smem + buf * 65536 + m * 32768 + h * 16384 + wv * 1024;
#pragma unroll
        for (int q = 0; q < 2; ++q) {
            int row = h * 128 + q * 64 + srow;
            const unsigned char* g =
                (const unsigned char*)(gb + (size_t)(off0 + row) * ld + ts * 64) + kbs;
            gld_lds16(g, lb + q * 8192);
        }
    };
    auto LDA4 = [&](bf16x8* dst, int fmb, int kk, lds_u8* Ab) {
#pragma unroll
        for (int f = 0; f < 4; ++f) {
            int r = wm * 128 + (fmb + f) * 16 + lm;
            dst[f] = *(lds_cvec*)(Ab + r * 128 + ((kk * 64 + kg16) ^ swz));
        }
    };
    auto LDB4 = [&](bf16x8* dst, int kk, lds_u8* Bb) {
#pragma unroll
        for (int f = 0; f < 4; ++f) {
            int c = wn * 64 + f * 16 + lm;
            dst[f] = *(lds_cvec*)(Bb + c * 128 + ((kk * 64 + kg16) ^ swz));
        }
    };

    // swapped operands: D frag = C^T block (rows=N, cols=M)
#define MM16(a4, b4, mo)                                                        \
    do {                                                                        \
        __builtin_amdgcn_s_setprio(1);                                          \
        _Pragma("unroll")                                                       \
        for (int fm = 0; fm < 4; ++fm)                                          \
            _Pragma("unroll")                                                   \
            for (int fn = 0; fn < 4; ++fn)                                      \
                acc[(mo) + fm][fn] = __builtin_amdgcn_mfma_f32_16x16x32_bf16(   \
                    (b4)[fn], (a4)[fm], acc[(mo) + fm][fn], 0, 0, 0);           \
        __builtin_amdgcn_s_setprio(0);                                          \
    } while (0)

    // phase tail: drain own ds_reads, pin so nothing crosses, then the single
    // per-phase barrier. PHEND_VM2 also drains vmem to 2 outstanding
    // (buffer publish, per R10 ledger).
#define PHEND()                                                     \
    do {                                                            \
        asm volatile("s_waitcnt lgkmcnt(0)");                       \
        __builtin_amdgcn_sched_barrier(0);                          \
        __builtin_amdgcn_s_barrier();                               \
    } while (0)
#define PHEND_VM2()                                                 \
    do {                                                            \
        asm volatile("s_waitcnt vmcnt(2) lgkmcnt(0)");              \
        __builtin_amdgcn_sched_barrier(0);                          \
        __builtin_amdgcn_s_barrier();                               \
    } while (0)

    const int NT = Kdim >> 6;   // K-tiles of 64 (even, >= 8 here)
    const int NI = NT >> 1;

    // prologue: t0 {Bl,Bh,Al,Ah} -> buf0, t1 {Bl,Bh} -> buf1  (12 loads)
    STAGE(0, 1, 0, 0); STAGE(0, 1, 0, 1);
    STAGE(0, 0, 0, 0); STAGE(0, 0, 0, 1);
    STAGE(1, 1, 1, 0); STAGE(1, 1, 1, 1);
    asm volatile("s_waitcnt vmcnt(4)");      // t0 fully landed
    __builtin_amdgcn_s_barrier();

    bf16x8 a03[4], a47[4], b0[4], b1[4];
    // pre-read ph1 frags (tile 0, kk0, buf0)
    LDB4(b0, 0, B0); LDA4(a03, 0, 0, A0);

    for (int i = 0; i < NI; ++i) {
        const int t = 2 * i;
        const int t1s = t + 1;                       // always < NT
        const int t2s = (t + 2 < NT) ? t + 2 : NT - 1;
        const int t3s = (t + 3 < NT) ? t + 3 : NT - 1;

        // ph1
        STAGE(t1s, 0, 1, 0);
        LDA4(a47, 4, 0, A0);
        MM16(a03, b0, 0);
        PHEND();
        // ph2
        STAGE(t1s, 0, 1, 1);
        LDA4(a03, 0, 1, A0); LDB4(b1, 1, B0);
        MM16(a47, b0, 4);
        PHEND();
        // ph3  (publishes buf1 = tile t+1)
        STAGE(t2s, 1, 0, 0);
        LDA4(a47, 4, 1, A0);
        MM16(a03, b1, 0);
        PHEND_VM2();
        // ph4
        STAGE(t2s, 1, 0, 1);
        LDA4(a03, 0, 0, A1); LDB4(b0, 0, B1);
        MM16(a47, b1, 4);
        PHEND();
        // ph5
        STAGE(t2s, 0, 0, 0);
        LDA4(a47, 4, 0, A1);
        MM16(a03, b0, 0);
        PHEND();
        // ph6
        STAGE(t2s, 0, 0, 1);
        LDA4(a03, 0, 1, A1); LDB4(b1, 1, B1);
        MM16(a47, b0, 4);
        PHEND();
        // ph7  (publishes buf0 = tile t+2)
        STAGE(t3s, 1, 1, 0);
        LDA4(a47, 4, 1, A1);
        MM16(a03, b1, 0);
        PHEND_VM2();
        // ph8
        STAGE(t3s, 1, 1, 1);
        LDA4(a03, 0, 0, A0); LDB4(b0, 0, B0);   // next tile's ph1 frags
        MM16(a47, b1, 4);
        PHEND();
    }

    asm volatile("s_waitcnt vmcnt(0)");

    // ---- epilogue (swapped layout): frag (fm,fn):
    // row m = bm + wm*128 + fm*16 + lm ; cols n = bn + wn*64 + fn*16 + (lane>>4)*4
    const int hi4 = (lane >> 4) * 4;
#pragma unroll
    for (int fm = 0; fm < 8; ++fm) {
        const int gr = bm + wm * 128 + fm * 16 + lm;
        float rowsum = 0.f;
#pragma unroll
        for (int fn = 0; fn < 4; ++fn) {
            const int gcn = bn + wn * 64 + fn * 16 + hi4;
            f32x4 v = acc[fm][fn];
            if (actv) {
#pragma unroll
                for (int e = 0; e < 4; ++e) v[e] = fmaxf(v[e], 0.f) + 1.f;
            }
            if (dacc) rowsum += v[0] + v[1] + v[2] + v[3];
            if (SCALE) {
                float4 d4 = *(const float4*)&denb[gcn];
                v[0] *= 1.f / (d4.x + EPSF);
                v[1] *= 1.f / (d4.y + EPSF);
                v[2] *= 1.f / (d4.z + EPSF);
                v[3] *= 1.f / (d4.w + EPSF);
            }
            if (OUT_BF16) {
                ushort4 o;
                o.x = f2bf(v[0]); o.y = f2bf(v[1]); o.z = f2bf(v[2]); o.w = f2bf(v[3]);
                *(ushort4*)((unsigned short*)Cout + coff + (size_t)gr * ldcr + gcn) = o;
            } else {
                *(float4*)((float*)Cout + coff + (size_t)gr * ldcr + gcn) =
                    *(float4*)&v;
            }
        }
        if (dacc) {
            // lanes {lm, lm+16, lm+32, lm+48} share gr; reduce across them
            rowsum += __shfl_xor(rowsum, 16, 64);
            rowsum += __shfl_xor(rowsum, 32, 64);
            if (lane < 16) atomicAdd(denw + (size_t)zb * Ff + gr, rowsum);
        }
    }
#undef MM16
#undef PHEND
#undef PHEND_VM2
}

// ---------------------------------------------------------------------------
extern "C" void kernel_launch(void* const* d_in, const int* in_sizes, int n_in,
                              void* d_out, int out_size, void* d_ws, size_t ws_size,
                              hipStream_t stream)
{
    (void)in_sizes; (void)n_in; (void)out_size;
    const float* x  = (const float*)d_in[0];
    const float* Wq = (const float*)d_in[1];
    const float* Wk = (const float*)d_in[2];
    const float* Wv = (const float*)d_in[3];
    float* out = (float*)d_out;

    const size_t nx   = (size_t)Bb * Ss * Dd;
    const size_t nW   = (size_t)3 * Dd * Ff;
    const size_t nQKV = (size_t)Bb * Ss * Ff;
    const size_t nCtx = (size_t)Bb * Ff * Ff;
    const size_t nP   = (size_t)16 * Ff * Ff;   // split-K partials (bf16)

    unsigned short* xb   = (unsigned short*)d_ws;          // [B][S][D]
    unsigned short* WT   = xb + nx;                        // [3][F][D] (Wq,Wk,Wv)
    unsigned short* Qb   = WT + nW;                        // [B][S][F] (relu1, unscaled)
    unsigned short* KbT  = Qb + nQKV;                      // [B][F][S] (= Qb + 1*B*S*F)
    unsigned short* VbT  = KbT + nQKV;                     // [B][F][S] (= Qb + 2*B*S*F)
    unsigned short* ctxb = VbT + nQKV;                     // [B][F][F] (den-scaled)
    float* den = (float*)(ctxb + nCtx);                    // [B][F]
    unsigned short* pctx = (unsigned short*)(den + (size_t)Bb * Ff); // [16][F][F]

    const size_t need_split =
        ((nx + nW + 3 * nQKV + nCtx + nP) * 2 + (size_t)Bb * Ff * 4);
    const bool do_split = ws_size >= need_split;

    // den accumulated by K-projection epilogue atomics — zero it first.
    hipMemsetAsync(den, 0, (size_t)Bb * Ff * sizeof(float), stream);

    cvt_x_kernel<<<dim3((int)(nx / 4 / 256)), 256, 0, stream>>>(x, xb, (int)(nx / 4));
    cvt_wT_kernel<<<dim3(Ff / 32, Dd / 32, 3), 256, 0, stream>>>(Wq, Wk, Wv, WT);

    // Merged Q+K+V projections (QKV=1): z = 3*b + pid.
    //  pid0 -> Qb[S][F] (relu1, no scale);  pid1 -> KbT[F][S] (relu1 + den
    //  atomics);  pid2 -> VbT[F][S] (plain). A=WT base, Bt=xb, Cout=Qb.
    gemm8<0, 0, 1, 0, 0, 1><<<dim3(Ss / 256, Ff / 256, 3 * Bb), 512, 0, stream>>>(
        WT, xb, Qb, nullptr, den,
        Dd, Dd, 0, Dd, 0, 0, 0);

    // ctx[f][g] = (K^T V)/(den[g]+eps)
    if (do_split) {
        // split-K=2 partials (unscaled), then add+scale
        gemm8<0, 0, 1, 1, 0, 0><<<dim3(Ff / 256, Ff / 256, 2 * Bb), 512, 0, stream>>>(
            KbT, VbT, pctx, nullptr, nullptr,
            Ss, Ss, Ff, Ss / 2, (size_t)Ff * Ss, (size_t)Ff * Ss, (size_t)Ff * Ff);
        add_ctx_kernel<<<dim3(Ff * Ff / 8 / 256, Bb), 256, 0, stream>>>(pctx, ctxb, den);
    } else {
        // non-split: scale in GEMM epilogue (den complete after projections)
        gemm8<0, 1, 1, 0, 0, 0><<<dim3(Ff / 256, Ff / 256, Bb), 512, 0, stream>>>(
            KbT, VbT, ctxb, den, nullptr,
            Ss, Ss, Ff, Ss, (size_t)Ff * Ss, (size_t)Ff * Ss, (size_t)Ff * Ff);
    }

    // out[f][s] = ctx @ Q^T (fp32 out)
    gemm8<0, 0, 0, 0, 0, 0><<<dim3(Ss / 256, Ff / 256, Bb), 512, 0, stream>>>(
        ctxb, Qb, out, nullptr, nullptr,
        Ff, Ff, Ss, Ff, (size_t)Ff * Ff, (size_t)Ss * Ff, (size_t)Ff * Ss);
}